// Round 4
// baseline (416.430 us; speedup 1.0000x reference)
//
#include <hip/hip_runtime.h>
#include <stdint.h>

#define DIN 256
#define DOUT 64
#define LMAX 50
#define NEG_INF -1e9f
#define WSTRIDE 264   // bf16 elems per W row in LDS (264 words/2=132 -> frag reads bank-uniform)

typedef short bf16x8 __attribute__((ext_vector_type(8)));
typedef float f32x4  __attribute__((ext_vector_type(4)));

static __device__ __forceinline__ unsigned short f2bf(float x) {
    unsigned int u = __float_as_uint(x);
    u += 0x7fffu + ((u >> 16) & 1u);     // RNE
    return (unsigned short)(u >> 16);
}
static __device__ __forceinline__ float bflo(unsigned int u) { return __uint_as_float(u << 16); }
static __device__ __forceinline__ float bfhi(unsigned int u) { return __uint_as_float(u & 0xffff0000u); }

// ---------------------------------------------------------------------------
// Kernel 1: projection via bf16 MFMA 16x16x32.
// Block = 256 thr (4 waves), tile 128 m x 64 n. W converted to bf16 LDS once
// ([n][k], stride 264); A-frags loaded straight from global (each element
// read exactly once per block; no per-chunk LDS or barriers).
// Frag layouts (m89/m120-verified): A[m=lane&15][k=quad*8+j],
// B[k=quad*8+j][n=lane&15], C/D[row=quad*4+reg][col=lane&15].
// ---------------------------------------------------------------------------
__global__ __launch_bounds__(256) void proj_kernel(
    const float* __restrict__ embed, const float* __restrict__ W,
    unsigned short* __restrict__ ep16, int N)
{
    __shared__ unsigned short wl[64 * WSTRIDE];   // 33,792 B -> 4 blocks/CU

    const int tid  = threadIdx.x;
    const int lane = tid & 63;
    const int wv   = tid >> 6;
    const int mrow = lane & 15;
    const int quad = lane >> 4;

    // ---- one-time W stage: fp32 -> bf16, layout wl[n*264 + k] ----
#pragma unroll
    for (int i = 0; i < 16; ++i) {
        const int idx4 = tid + 256 * i;          // float4 index, coalesced
        const int e    = idx4 * 4;               // element = n*256 + k
        const int n    = e >> 8;
        const int k    = e & 255;
        const float4 f = *(const float4*)&W[e];
        union { unsigned short s[4]; unsigned long long v; } p;
        p.s[0] = f2bf(f.x); p.s[1] = f2bf(f.y);
        p.s[2] = f2bf(f.z); p.s[3] = f2bf(f.w);
        *(unsigned long long*)&wl[n * WSTRIDE + k] = p.v;
    }
    __syncthreads();

    const int m_base = blockIdx.x * 128 + wv * 32;

    f32x4 acc[2][4];
#pragma unroll
    for (int mt = 0; mt < 2; ++mt)
#pragma unroll
        for (int nt = 0; nt < 4; ++nt) acc[mt][nt] = (f32x4){0.f, 0.f, 0.f, 0.f};

    for (int kc = 0; kc < DIN; kc += 32) {
        // A-frags direct from global: lane reads 32 contiguous bytes of row m
        bf16x8 afrag[2];
#pragma unroll
        for (int mt = 0; mt < 2; ++mt) {
            int row = m_base + mt * 16 + mrow;
            if (row >= N) row = N - 1;                    // clamp; store-guarded
            const float* ap = embed + (size_t)row * DIN + kc + quad * 8;
            const float4 f0 = *(const float4*)ap;
            const float4 f1 = *(const float4*)(ap + 4);
            union { short s[8]; bf16x8 f; } a;
            a.s[0] = (short)f2bf(f0.x); a.s[1] = (short)f2bf(f0.y);
            a.s[2] = (short)f2bf(f0.z); a.s[3] = (short)f2bf(f0.w);
            a.s[4] = (short)f2bf(f1.x); a.s[5] = (short)f2bf(f1.y);
            a.s[6] = (short)f2bf(f1.z); a.s[7] = (short)f2bf(f1.w);
            afrag[mt] = a.f;
        }
#pragma unroll
        for (int nt = 0; nt < 4; ++nt) {
            const bf16x8 bfrag =
                *(const bf16x8*)&wl[(nt * 16 + mrow) * WSTRIDE + kc + quad * 8];
            acc[0][nt] = __builtin_amdgcn_mfma_f32_16x16x32_bf16(
                afrag[0], bfrag, acc[0][nt], 0, 0, 0);
            acc[1][nt] = __builtin_amdgcn_mfma_f32_16x16x32_bf16(
                afrag[1], bfrag, acc[1][nt], 0, 0, 0);
        }
    }

    // ---- epilogue: C/D[row=quad*4+r][col=lane&15] -> bf16 store ----
#pragma unroll
    for (int mt = 0; mt < 2; ++mt)
#pragma unroll
        for (int nt = 0; nt < 4; ++nt)
#pragma unroll
            for (int r = 0; r < 4; ++r) {
                const int row = m_base + mt * 16 + quad * 4 + r;
                if (row < N)
                    ep16[(size_t)row * DOUT + nt * 16 + mrow] = f2bf(acc[mt][nt][r]);
            }
}

// ---------------------------------------------------------------------------
// Kernel 2: GAT attention + aggregation. 1 wave per 2 nodes, barrier-free
// double-buffered DMA pipeline (per-wave s_waitcnt vmcnt(0) via inline asm).
// Rows stored chunk-XOR-rotated (stored chunk sc holds global chunk sc^(r&7))
// so phase 1 reads uniform k-octets as bank-uniform b128 with a_src in SGPRs.
// ---------------------------------------------------------------------------
struct NodePrep { bool mvalid; unsigned int du; };

__global__ __launch_bounds__(256) void agg_kernel(
    const int* __restrict__ neighs, const void* __restrict__ mask,
    const int* __restrict__ dst_idx, const unsigned int* __restrict__ ep16u,
    const float* __restrict__ a_src, const float* __restrict__ a_dst,
    float* __restrict__ out, int B)
{
    __shared__ unsigned int fwbuf[4][2][LMAX * 32];   // 51,200 B
    __shared__ float attn_s[4][64];

    const int tid  = threadIdx.x;
    const int lane = tid & 63;
    const int wv   = tid >> 6;
    const int gw   = blockIdx.x * 4 + wv;    // wave id; handles nodes 2gw, 2gw+1
    const int c    = lane & 31;

    // mask storage-format detection: flat element 50 (row1,col0) always True.
    const unsigned int* mw = (const unsigned int*)mask;
    const bool byteMode = (mw[12] > 1u);

    const float2 adv = *(const float2*)&a_dst[2 * c];

    // DMA chunk permutation (independent of row-group index i):
    const int gchunk = (lane & 7) ^ (lane >> 3);

    auto prep_and_dma = [&](int node, unsigned int* buf) -> NodePrep {
        NodePrep p;
        const int* nb = neighs + (size_t)node * LMAX;
        p.mvalid = false;
        if (lane < LMAX) {
            const int mi = node * LMAX + lane;
            p.mvalid = byteMode ? (((const uint8_t*)mask)[mi] != 0)
                                : (((const int*)mask)[mi] != 0);
        }
        const unsigned long long vm = __ballot(p.mvalid);
        const int n0 = nb[0];                           // always valid
        // 6 x width-16 DMA: rows 0..47, chunk-rotated by row&7
#pragma unroll
        for (int i = 0; i < 6; ++i) {
            const int r = 8 * i + (lane >> 3);
            const int n = ((vm >> r) & 1ull) ? nb[r] : n0;
            const unsigned int* gp = ep16u + (size_t)n * 32 + gchunk * 4;
            __builtin_amdgcn_global_load_lds(
                (const __attribute__((address_space(1))) void*)gp,
                (__attribute__((address_space(3))) void*)&buf[i * 256],
                16, 0, 0);
        }
        {   // rows 48,49: width-4, word-level rotated addressing
            const int r  = 48 + (lane >> 5);            // rho = r&7 = lane>>5
            const int n  = ((vm >> r) & 1ull) ? nb[r] : n0;
            const int w  = lane & 31;
            const int gwd = (((w >> 2) ^ (r & 7)) << 2) + (w & 3);
            const unsigned int* gp = ep16u + (size_t)n * 32 + gwd;
            __builtin_amdgcn_global_load_lds(
                (const __attribute__((address_space(1))) void*)gp,
                (__attribute__((address_space(3))) void*)&buf[48 * 32],
                4, 0, 0);
        }
        // dst row (bf16 pair per lane; halves duplicate)
        p.du = ep16u[(size_t)dst_idx[node] * 32 + c];
        return p;
    };

    auto compute_store = [&](int node, const unsigned int* buf, const NodePrep& p) {
        // dst attention
        float pd = bflo(p.du) * adv.x + bfhi(p.du) * adv.y;
#pragma unroll
        for (int m = 32; m >= 1; m >>= 1) pd += __shfl_xor(pd, m, 64);
        pd *= 0.5f;
        const float dst_attn = pd >= 0.f ? pd : 0.2f * pd;

        // phase 1: uniform k-octets, b128 reads, a_src via scalar loads
        const int l    = lane < LMAX ? lane : 0;
        const int rot7 = l & 7;
        const unsigned int* fr = buf + l * 32;
        float dot = 0.f;
#pragma unroll
        for (int k8 = 0; k8 < 8; ++k8) {
            const uint4 u = *(const uint4*)&fr[((k8 ^ rot7) << 2)];
            dot = fmaf(bflo(u.x), a_src[k8 * 8 + 0], dot);
            dot = fmaf(bfhi(u.x), a_src[k8 * 8 + 1], dot);
            dot = fmaf(bflo(u.y), a_src[k8 * 8 + 2], dot);
            dot = fmaf(bfhi(u.y), a_src[k8 * 8 + 3], dot);
            dot = fmaf(bflo(u.z), a_src[k8 * 8 + 4], dot);
            dot = fmaf(bfhi(u.z), a_src[k8 * 8 + 5], dot);
            dot = fmaf(bflo(u.w), a_src[k8 * 8 + 6], dot);
            dot = fmaf(bfhi(u.w), a_src[k8 * 8 + 7], dot);
        }
        const float lr = dot >= 0.f ? dot : 0.2f * dot;
        float s = (lane < LMAX && p.mvalid) ? (dst_attn + lr) : NEG_INF;

        float mx = s;
#pragma unroll
        for (int m = 32; m >= 1; m >>= 1) mx = fmaxf(mx, __shfl_xor(mx, m, 64));
        const float e = __expf(s - mx);                 // masked lanes -> exactly 0
        float se = e;
#pragma unroll
        for (int m = 32; m >= 1; m >>= 1) se += __shfl_xor(se, m, 64);
        attn_s[wv][lane] = e / se;                      // same-wave write/read

        // phase 2: 2 rows/iter, word-rotated b32 reads (2-way, free)
        const int half = lane >> 5;
        float acc0 = 0.f, acc1 = 0.f;
#pragma unroll
        for (int i = 0; i < 25; ++i) {
            const int r  = 2 * i + half;
            const int sw = (((c >> 2) ^ (r & 7)) << 2) + (c & 3);
            const unsigned int u = buf[r * 32 + sw];
            const float w = attn_s[wv][r];
            acc0 = fmaf(w, bflo(u), acc0);
            acc1 = fmaf(w, bfhi(u), acc1);
        }
        acc0 += __shfl_xor(acc0, 32, 64);
        acc1 += __shfl_xor(acc1, 32, 64);
        if (lane < 32) {
            float2 o; o.x = acc0; o.y = acc1;
            *(float2*)&out[(size_t)node * DOUT + 2 * c] = o;
        }
    };

    const int b0 = 2 * gw, b1 = 2 * gw + 1;
    const int b0c = b0 < B ? b0 : B - 1;
    const int b1c = b1 < B ? b1 : B - 1;

    NodePrep p0 = prep_and_dma(b0c, &fwbuf[wv][0][0]);
    asm volatile("s_waitcnt vmcnt(0)" ::: "memory");     // drain node-0 DMAs
    NodePrep p1 = prep_and_dma(b1c, &fwbuf[wv][1][0]);   // node-1 DMAs in flight
    if (b0 < B) compute_store(b0, &fwbuf[wv][0][0], p0); // overlaps node-1 DMA
    asm volatile("s_waitcnt vmcnt(0)" ::: "memory");     // drain node-1 DMAs
    if (b1 < B) compute_store(b1, &fwbuf[wv][1][0], p1);
}

// ---------------------------------------------------------------------------
extern "C" void kernel_launch(void* const* d_in, const int* in_sizes, int n_in,
                              void* d_out, int out_size, void* d_ws, size_t ws_size,
                              hipStream_t stream)
{
    const int*   neighs  = (const int*)d_in[0];
    const void*  mask    = d_in[1];
    const int*   dst_idx = (const int*)d_in[2];
    const float* embed   = (const float*)d_in[3];
    const float* W       = (const float*)d_in[4];
    const float* a_src   = (const float*)d_in[5];
    const float* a_dst   = (const float*)d_in[6];
    float* out = (float*)d_out;

    const int B = in_sizes[2];            // 50000
    const int N = in_sizes[3] / DIN;      // 200000

    unsigned short* ep16 = (unsigned short*)d_ws;   // N*64*2 = 25.6 MB

    proj_kernel<<<dim3((N + 127) / 128), dim3(256), 0, stream>>>(embed, W, ep16, N);

    const int waves = (B + 1) / 2;                  // 2 nodes per wave
    agg_kernel<<<dim3((waves + 3) / 4), dim3(256), 0, stream>>>(
        neighs, mask, dst_idx, (const unsigned int*)ep16, a_src, a_dst, out, B);
}

// Round 5
// 374.757 us; speedup vs baseline: 1.1112x; 1.1112x over previous
//
#include <hip/hip_runtime.h>
#include <stdint.h>

#define DIN 256
#define DOUT 64
#define LMAX 50
#define NEG_INF -1e9f
#define WSTRIDE 264   // bf16 elems per W row in LDS

typedef short bf16x8 __attribute__((ext_vector_type(8)));
typedef float f32x4  __attribute__((ext_vector_type(4)));

static __device__ __forceinline__ unsigned short f2bf(float x) {
    unsigned int u = __float_as_uint(x);
    u += 0x7fffu + ((u >> 16) & 1u);     // RNE
    return (unsigned short)(u >> 16);
}
static __device__ __forceinline__ float bflo(unsigned int u) { return __uint_as_float(u << 16); }
static __device__ __forceinline__ float bfhi(unsigned int u) { return __uint_as_float(u & 0xffff0000u); }

// ---------------------------------------------------------------------------
// Kernel 1: projection via bf16 MFMA 16x16x32 (UNCHANGED from round 4).
// Block = 256 thr (4 waves), tile 128 m x 64 n. W converted to bf16 LDS once
// ([n][k], stride 264); A-frags loaded straight from global (each element
// read exactly once per block; no per-chunk LDS or barriers).
// ---------------------------------------------------------------------------
__global__ __launch_bounds__(256) void proj_kernel(
    const float* __restrict__ embed, const float* __restrict__ W,
    unsigned short* __restrict__ ep16, int N)
{
    __shared__ unsigned short wl[64 * WSTRIDE];   // 33,792 B -> 4 blocks/CU

    const int tid  = threadIdx.x;
    const int lane = tid & 63;
    const int wv   = tid >> 6;
    const int mrow = lane & 15;
    const int quad = lane >> 4;

    // ---- one-time W stage: fp32 -> bf16, layout wl[n*264 + k] ----
#pragma unroll
    for (int i = 0; i < 16; ++i) {
        const int idx4 = tid + 256 * i;          // float4 index, coalesced
        const int e    = idx4 * 4;               // element = n*256 + k
        const int n    = e >> 8;
        const int k    = e & 255;
        const float4 f = *(const float4*)&W[e];
        union { unsigned short s[4]; unsigned long long v; } p;
        p.s[0] = f2bf(f.x); p.s[1] = f2bf(f.y);
        p.s[2] = f2bf(f.z); p.s[3] = f2bf(f.w);
        *(unsigned long long*)&wl[n * WSTRIDE + k] = p.v;
    }
    __syncthreads();

    const int m_base = blockIdx.x * 128 + wv * 32;

    f32x4 acc[2][4];
#pragma unroll
    for (int mt = 0; mt < 2; ++mt)
#pragma unroll
        for (int nt = 0; nt < 4; ++nt) acc[mt][nt] = (f32x4){0.f, 0.f, 0.f, 0.f};

    for (int kc = 0; kc < DIN; kc += 32) {
        bf16x8 afrag[2];
#pragma unroll
        for (int mt = 0; mt < 2; ++mt) {
            int row = m_base + mt * 16 + mrow;
            if (row >= N) row = N - 1;                    // clamp; store-guarded
            const float* ap = embed + (size_t)row * DIN + kc + quad * 8;
            const float4 f0 = *(const float4*)ap;
            const float4 f1 = *(const float4*)(ap + 4);
            union { short s[8]; bf16x8 f; } a;
            a.s[0] = (short)f2bf(f0.x); a.s[1] = (short)f2bf(f0.y);
            a.s[2] = (short)f2bf(f0.z); a.s[3] = (short)f2bf(f0.w);
            a.s[4] = (short)f2bf(f1.x); a.s[5] = (short)f2bf(f1.y);
            a.s[6] = (short)f2bf(f1.z); a.s[7] = (short)f2bf(f1.w);
            afrag[mt] = a.f;
        }
#pragma unroll
        for (int nt = 0; nt < 4; ++nt) {
            const bf16x8 bfrag =
                *(const bf16x8*)&wl[(nt * 16 + mrow) * WSTRIDE + kc + quad * 8];
            acc[0][nt] = __builtin_amdgcn_mfma_f32_16x16x32_bf16(
                afrag[0], bfrag, acc[0][nt], 0, 0, 0);
            acc[1][nt] = __builtin_amdgcn_mfma_f32_16x16x32_bf16(
                afrag[1], bfrag, acc[1][nt], 0, 0, 0);
        }
    }

#pragma unroll
    for (int mt = 0; mt < 2; ++mt)
#pragma unroll
        for (int nt = 0; nt < 4; ++nt)
#pragma unroll
            for (int r = 0; r < 4; ++r) {
                const int row = m_base + mt * 16 + quad * 4 + r;
                if (row < N)
                    ep16[(size_t)row * DOUT + nt * 16 + mrow] = f2bf(acc[mt][nt][r]);
            }
}

// ---------------------------------------------------------------------------
// Kernel 2: GAT attention + aggregation.
// Round-3 structure (1 node/wave, 4 nodes/block, 26.6 KB LDS -> 6 blocks/CU,
// 75% occupancy) + round-4 improvements (XOR-swizzled DMA layout so phase 1
// reads uniform k-octets as bank-uniform b128 with a_src as scalar operands).
// ---------------------------------------------------------------------------
__global__ __launch_bounds__(256, 6) void agg_kernel(
    const int* __restrict__ neighs, const void* __restrict__ mask,
    const int* __restrict__ dst_idx, const unsigned int* __restrict__ ep16u,
    const float* __restrict__ a_src, const float* __restrict__ a_dst,
    float* __restrict__ out, int B)
{
    __shared__ unsigned int fwbuf[4][LMAX * 32];   // 25,600 B
    __shared__ float attn_s[4][64];                //  1,024 B

    const int tid  = threadIdx.x;
    const int lane = tid & 63;
    const int wv   = tid >> 6;
    const int b    = blockIdx.x * 4 + wv;
    const int bc   = b < B ? b : B - 1;            // clamp (grid exact for B=50000)
    const int c    = lane & 31;

    // mask storage-format detection: flat element 50 (row1,col0) always True.
    const unsigned int* mw = (const unsigned int*)mask;
    const bool byteMode = (mw[12] > 1u);

    // per-lane neighbor mask (lane = l)
    bool mvalid = false;
    if (lane < LMAX) {
        const int mi = bc * LMAX + lane;
        mvalid = byteMode ? (((const uint8_t*)mask)[mi] != 0)
                          : (((const int*)mask)[mi] != 0);
    }
    const unsigned long long vm = __ballot(mvalid);

    const int* nb = neighs + (size_t)bc * LMAX;
    const int n0  = nb[0];                         // always valid

    // dst row load early (ordinary global load; shares vmcnt FIFO)
    const unsigned int du = ep16u[(size_t)dst_idx[bc] * 32 + c];
    const float2 adv = *(const float2*)&a_dst[2 * c];

    // ---- async gather, chunk-XOR-rotated layout ----
    // stored 16B-chunk sc of row r holds global chunk sc ^ (r&7)
    unsigned int* buf = fwbuf[wv];
    const int gchunk = (lane & 7) ^ (lane >> 3);   // rho = (lane>>3)&7 = row&7
#pragma unroll
    for (int i = 0; i < 6; ++i) {
        const int r = 8 * i + (lane >> 3);
        const int n = ((vm >> r) & 1ull) ? nb[r] : n0;
        const unsigned int* gp = ep16u + (size_t)n * 32 + gchunk * 4;
        __builtin_amdgcn_global_load_lds(
            (const __attribute__((address_space(1))) void*)gp,
            (__attribute__((address_space(3))) void*)&buf[i * 256],
            16, 0, 0);
    }
    {   // rows 48,49: width-4, word-level rotated addressing
        const int r   = 48 + (lane >> 5);          // r&7 = lane>>5
        const int n   = ((vm >> r) & 1ull) ? nb[r] : n0;
        const int w   = lane & 31;
        const int gwd = (((w >> 2) ^ (r & 7)) << 2) + (w & 3);
        const unsigned int* gp = ep16u + (size_t)n * 32 + gwd;
        __builtin_amdgcn_global_load_lds(
            (const __attribute__((address_space(1))) void*)gp,
            (__attribute__((address_space(3))) void*)&buf[48 * 32],
            4, 0, 0);
    }

    // ---- dst attention while DMAs fly (halves duplicate; sum = 2x dot) ----
    float pd = bflo(du) * adv.x + bfhi(du) * adv.y;
#pragma unroll
    for (int m = 32; m >= 1; m >>= 1) pd += __shfl_xor(pd, m, 64);
    pd *= 0.5f;
    const float dst_attn = pd >= 0.f ? pd : 0.2f * pd;

    __syncthreads();   // per-wave vmcnt drain + block barrier

    // ---- phase 1: uniform k-octets, bank-uniform b128, a_src in SGPRs ----
    const int l    = lane < LMAX ? lane : 0;
    const int rot7 = l & 7;
    const unsigned int* fr = buf + l * 32;
    float dot = 0.f;
#pragma unroll
    for (int k8 = 0; k8 < 8; ++k8) {
        const uint4 u = *(const uint4*)&fr[((k8 ^ rot7) << 2)];
        dot = fmaf(bflo(u.x), a_src[k8 * 8 + 0], dot);
        dot = fmaf(bfhi(u.x), a_src[k8 * 8 + 1], dot);
        dot = fmaf(bflo(u.y), a_src[k8 * 8 + 2], dot);
        dot = fmaf(bfhi(u.y), a_src[k8 * 8 + 3], dot);
        dot = fmaf(bflo(u.z), a_src[k8 * 8 + 4], dot);
        dot = fmaf(bfhi(u.z), a_src[k8 * 8 + 5], dot);
        dot = fmaf(bflo(u.w), a_src[k8 * 8 + 6], dot);
        dot = fmaf(bfhi(u.w), a_src[k8 * 8 + 7], dot);
    }
    const float lr = dot >= 0.f ? dot : 0.2f * dot;
    float s = (lane < LMAX && mvalid) ? (dst_attn + lr) : NEG_INF;

    float mx = s;
#pragma unroll
    for (int m = 32; m >= 1; m >>= 1) mx = fmaxf(mx, __shfl_xor(mx, m, 64));
    const float e = __expf(s - mx);                // masked lanes -> exactly 0
    float se = e;
#pragma unroll
    for (int m = 32; m >= 1; m >>= 1) se += __shfl_xor(se, m, 64);
    attn_s[wv][lane] = e / se;                     // same-wave write/read

    // ---- phase 2: 2 rows/iter, word-rotated b32 reads (2-way, free) ----
    const int half = lane >> 5;
    float acc0 = 0.f, acc1 = 0.f;
#pragma unroll
    for (int i = 0; i < 25; ++i) {
        const int r  = 2 * i + half;
        const int sw = (((c >> 2) ^ (r & 7)) << 2) + (c & 3);
        const unsigned int u = buf[r * 32 + sw];
        const float w = attn_s[wv][r];
        acc0 = fmaf(w, bflo(u), acc0);
        acc1 = fmaf(w, bfhi(u), acc1);
    }
    acc0 += __shfl_xor(acc0, 32, 64);              // even-rows + odd-rows half
    acc1 += __shfl_xor(acc1, 32, 64);
    if (b < B && lane < 32) {
        float2 o; o.x = acc0; o.y = acc1;
        *(float2*)&out[(size_t)b * DOUT + 2 * c] = o;
    }
}

// ---------------------------------------------------------------------------
extern "C" void kernel_launch(void* const* d_in, const int* in_sizes, int n_in,
                              void* d_out, int out_size, void* d_ws, size_t ws_size,
                              hipStream_t stream)
{
    const int*   neighs  = (const int*)d_in[0];
    const void*  mask    = d_in[1];
    const int*   dst_idx = (const int*)d_in[2];
    const float* embed   = (const float*)d_in[3];
    const float* W       = (const float*)d_in[4];
    const float* a_src   = (const float*)d_in[5];
    const float* a_dst   = (const float*)d_in[6];
    float* out = (float*)d_out;

    const int B = in_sizes[2];            // 50000
    const int N = in_sizes[3] / DIN;      // 200000

    unsigned short* ep16 = (unsigned short*)d_ws;   // N*64*2 = 25.6 MB

    proj_kernel<<<dim3((N + 127) / 128), dim3(256), 0, stream>>>(embed, W, ep16, N);
    agg_kernel<<<dim3((B + 3) / 4), dim3(256), 0, stream>>>(
        neighs, mask, dst_idx, (const unsigned int*)ep16, a_src, a_dst, out, B);
}